// Round 7
// baseline (308.516 us; speedup 1.0000x reference)
//
#include <hip/hip_runtime.h>

// ---------------------------------------------------------------------------
// PositionEncoder: per token (B*T = 262144), output 272 f32:
//   x[0:6] | emb[idx1] (128) | x[6:10] | emb[idx2] (128) | x[10:16]
// idx from matching (x[4],x[5]) / (x[8],x[9]) vs 26 nodes,
// close iff |p - node| <= 0.01 + 1e-5*|node| per dim; idx = first match + 1.
//
// R1 branchy gather; R2 LDS tile; R4 +nt; R5 half-row tasks (regressed);
// R6 wave-per-token register gather == R4 (0.25% apart) => both at the
// write-bound plateau; dur_us is dominated by fixed harness cost (poison
// fill ~178us + restore dispatches).
// R7: fuse idx compute into the writer. Each wave's 64 lanes evaluate all
// 64 (token, point) index tasks of its 32 tokens in ONE point_index pass,
// broadcast per-token via readlane (SGPR). Kills K1 launch + 4 MB ws
// traffic. Writer body identical to R6: per token one aligned 16B nt store
// per lane (cols [0,256)) + lanes 0-3 covering cols [256,272); all region
// boundaries even => no 8B chunk straddles a region (cndmask base select).
// ---------------------------------------------------------------------------

#define THREADS 256
#define TOK_PER_WAVE 32

typedef float vf2 __attribute__((ext_vector_type(2)));
typedef float vf4 __attribute__((ext_vector_type(4)));

constexpr float kNX[26] = {
    0.5454545454545454f, 0.6022727272727273f, 0.5454545454545454f,
    0.6022727272727273f, 0.4772727272727273f, 0.42045454545454547f,
    0.42045454545454547f, 0.4772727272727273f, 0.32954545454545453f,
    0.42045454545454547f, 0.4772727272727273f, 0.4772727272727273f,
    0.42045454545454547f, 0.32954545454545453f, 0.5727272727272728f,
    0.7613636363636364f, 0.8181818181818182f, 0.8181818181818182f,
    0.7613636363636364f, 0.7909090909090909f, 0.9431818181818182f,
    1.0f, 1.0f, 0.9431818181818182f, 0.9727272727272728f, 0.9727272727272728f};
constexpr float kNY[26] = {
    0.76f, 0.76f, 0.86f, 0.86f, 0.76f, 0.76f, 0.86f, 0.86f, 0.808f,
    0.48f, 0.48f, 0.38f, 0.38f, 0.428f, 0.62f, 0.76f, 0.76f, 0.86f,
    0.86f, 0.62f, 0.76f, 0.76f, 0.86f, 0.86f, 0.62f, 1.0f};

__device__ __forceinline__ int point_index(float px, float py) {
#pragma clang fp contract(off)
    int idx = 0;
    // Reverse iterate + overwrite => lowest-index match wins.
#pragma unroll
    for (int n = 25; n >= 0; --n) {
        float tx = 0.01f + 1.0e-5f * kNX[n];   // compile-time folded
        float ty = 0.01f + 1.0e-5f * kNY[n];
        bool c = (fabsf(px - kNX[n]) <= tx) && (fabsf(py - kNY[n]) <= ty);
        if (c) idx = n + 1;
    }
    return idx;
}

// chunk source: 2-col chunk starting at even col c never straddles a region
__device__ __forceinline__ const float* chunk_src(
    int c, const float* xr, const float* e1, const float* e2) {
    const float* p = xr + c;                 // c in [0,6)
    p = (c >= 6)   ? e1 + (c - 6)   : p;     // [6,134)   emb row 1
    p = (c >= 134) ? xr + (c - 128) : p;     // [134,138) x[6:10]
    p = (c >= 138) ? e2 + (c - 138) : p;     // [138,266) emb row 2
    p = (c >= 266) ? xr + (c - 256) : p;     // [266,272) x[10:16]
    return p;
}

// ---- fused kernel: one wave per 32 tokens, no LDS, no barriers ------------
__global__ __launch_bounds__(THREADS) void pos_enc_kernel(
    const float* __restrict__ x, const float* __restrict__ emb,
    float* __restrict__ out, int n_tokens) {
    const int lane = threadIdx.x & 63;
    const int wave = blockIdx.x * (THREADS / 64) + (threadIdx.x >> 6);
    const int t0   = wave * TOK_PER_WAVE;

    // --- phase 1: lane l computes index for (token t0+(l>>1), point l&1) ---
    int myidx = 0;
    {
        int tk  = t0 + (lane >> 1);
        int col = (lane & 1) ? 8 : 4;
        if (tk < n_tokens) {
            vf2 p = *(const vf2*)(x + (size_t)tk * 16 + col);  // 8B-aligned
            myidx = point_index(p.x, p.y);
        }
    }

    // --- phase 2: per token, gather + one aligned 16B nt store per lane ---
    const int c0 = 4 * lane;          // cols [c0, c0+4)
    const int cs = 256 + 4 * lane;    // lanes 0-3: cols [cs, cs+4)

#pragma unroll 4
    for (int it = 0; it < TOK_PER_WAVE; ++it) {
        int t = t0 + it;
        if (t >= n_tokens) break;
        int i1 = __builtin_amdgcn_readlane(myidx, 2 * it);      // SGPR bcast
        int i2 = __builtin_amdgcn_readlane(myidx, 2 * it + 1);
        const float* xr = x   + (size_t)t * 16;
        const float* e1 = emb + (size_t)i1 * 128;               // L2-hot
        const float* e2 = emb + (size_t)i2 * 128;
        float* orow = out + (size_t)t * 272;   // rows are 1088B = 17 lines

        vf2 a = *(const vf2*)chunk_src(c0,     xr, e1, e2);
        vf2 b = *(const vf2*)chunk_src(c0 + 2, xr, e1, e2);
        vf4 v;  v.x = a.x; v.y = a.y; v.z = b.x; v.w = b.y;
        __builtin_nontemporal_store(v, (vf4*)(orow + c0));

        if (lane < 4) {
            vf2 a2 = *(const vf2*)chunk_src(cs,     xr, e1, e2);
            vf2 b2 = *(const vf2*)chunk_src(cs + 2, xr, e1, e2);
            vf4 v2;  v2.x = a2.x; v2.y = a2.y; v2.z = b2.x; v2.w = b2.y;
            __builtin_nontemporal_store(v2, (vf4*)(orow + cs));
        }
    }
}

extern "C" void kernel_launch(void* const* d_in, const int* in_sizes, int n_in,
                              void* d_out, int out_size, void* d_ws, size_t ws_size,
                              hipStream_t stream) {
    const float* x   = (const float*)d_in[0];   // [B, T, 16] f32
    const float* emb = (const float*)d_in[1];   // [100, 128] f32
    float* out = (float*)d_out;                 // [B, T, 272] f32

    int n_tokens = in_sizes[0] / 16;            // 262144

    // one wave per 32 tokens: 8192 waves = 2048 blocks of 4 waves
    int waves = (n_tokens + TOK_PER_WAVE - 1) / TOK_PER_WAVE;
    int nblk  = (waves + (THREADS / 64) - 1) / (THREADS / 64);
    pos_enc_kernel<<<nblk, THREADS, 0, stream>>>(x, emb, out, n_tokens);
}